// Round 1
// 460.564 us; speedup vs baseline: 1.0706x; 1.0706x over previous
//
#include <hip/hip_runtime.h>
#include <stdint.h>

#define NCLS 19
#define HW   (768 * 768)          // 589824
#define NPIX (8 * HW)             // 4718592
#define NGRP (NPIX / 4)           // 1179648 groups of 4 pixels
#define MINKEPT 131072u
#define NBINS 8192
#define BLOCK 256
#define GRID_MAIN (NGRP / BLOCK)  // 4608 blocks, exactly 1 group per thread

// workspace layout (bytes) — all write-before-read, no memset required
#define OFF_PSUM  ((size_t)0)                          // GRID_MAIN f32 partial sums
#define OFF_PCS   ((size_t)GRID_MAIN * 4)              // GRID_MAIN u32 sel-cnt
#define OFF_PCV   ((size_t)GRID_MAIN * 8)              // GRID_MAIN u32 valid-cnt
#define OFF_STATE ((size_t)GRID_MAIN * 12)             // state words
#define OFF_PROB  (OFF_STATE + 256)                    // NPIX u32  (fallback only)
#define OFF_LOSS  (OFF_PROB + (size_t)NPIX * 4)        // NPIX f32  (fallback only)
#define OFF_HIST  (OFF_LOSS + (size_t)NPIX * 4)        // NBINS u32 (fallback only)
// state: [0]=pref [1]=krem [2]=thresh_bits [4]=flag_common [5]=k
//        [6..8]=hist/scan done-counters (levels 0..2)  [9]=reduce done-counter
//        all counters zeroed by k_decide (runs before any fallback kernel)

typedef float    f4 __attribute__((ext_vector_type(4)));
typedef int      i4 __attribute__((ext_vector_type(4)));
typedef unsigned u4 __attribute__((ext_vector_type(4)));

struct Grp { u4 pb; f4 lo; float ls; unsigned sc; unsigned vc; };

// Pure per-group function — fallback recompute is bit-identical to phase 1.
// predict/target are read-once streams -> nontemporal loads (no reuse; the
// inter-iteration workspace poison flushes L2/L3 anyway).
__device__ __forceinline__ Grp compute4(const float* __restrict__ predict,
                                        const int* __restrict__ target,
                                        const float* __restrict__ wsh, int g)
{
    int n = g / HW;
    int p = g - n * HW;
    const float* base = predict + (size_t)n * ((size_t)NCLS * HW) + p;

    i4 t4 = __builtin_nontemporal_load((const i4*)(target + g));
    int tcx = (t4.x == -1) ? 0 : t4.x;
    int tcy = (t4.y == -1) ? 0 : t4.y;
    int tcz = (t4.z == -1) ? 0 : t4.z;
    int tcw = (t4.w == -1) ? 0 : t4.w;

    f4 s  = {0.f, 0.f, 0.f, 0.f};
    f4 vt = {0.f, 0.f, 0.f, 0.f};
#pragma unroll
    for (int c = 0; c < NCLS; ++c) {
        f4 v = __builtin_nontemporal_load((const f4*)(base + (size_t)c * HW));
        s.x += __expf(v.x); s.y += __expf(v.y);
        s.z += __expf(v.z); s.w += __expf(v.w);
        vt.x = (c == tcx) ? v.x : vt.x;
        vt.y = (c == tcy) ? v.y : vt.y;
        vt.z = (c == tcz) ? v.z : vt.z;
        vt.w = (c == tcw) ? v.w : vt.w;
    }

    bool vx = (t4.x != -1), vy = (t4.y != -1), vz = (t4.z != -1), vw = (t4.w != -1);
    float lpx = vt.x - __logf(s.x), lpy = vt.y - __logf(s.y);
    float lpz = vt.z - __logf(s.z), lpw = vt.w - __logf(s.w);
    float px = __expf(lpx), py = __expf(lpy), pz = __expf(lpz), pw = __expf(lpw);

    Grp r;
    r.pb.x = vx ? __float_as_uint(px) : 0x7F800000u;
    r.pb.y = vy ? __float_as_uint(py) : 0x7F800000u;
    r.pb.z = vz ? __float_as_uint(pz) : 0x7F800000u;
    r.pb.w = vw ? __float_as_uint(pw) : 0x7F800000u;
    r.lo.x = vx ? (-wsh[tcx] * lpx) : 0.f;
    r.lo.y = vy ? (-wsh[tcy] * lpy) : 0.f;
    r.lo.z = vz ? (-wsh[tcz] * lpz) : 0.f;
    r.lo.w = vw ? (-wsh[tcw] * lpw) : 0.f;
    bool sx = vx && (px < 0.9f), sy = vy && (py < 0.9f);
    bool sz = vz && (pz < 0.9f), sw = vw && (pw < 0.9f);
    r.ls = (sx ? r.lo.x : 0.f) + (sy ? r.lo.y : 0.f) +
           (sz ? r.lo.z : 0.f) + (sw ? r.lo.w : 0.f);
    r.sc = (unsigned)sx + (unsigned)sy + (unsigned)sz + (unsigned)sw;
    r.vc = (unsigned)vx + (unsigned)vy + (unsigned)vz + (unsigned)vw;
    return r;
}

// ---------------------------------------------------------------------------
// K1: pure-read streaming pass. One 4-pixel group per thread; per-block
// partials (no atomics, no stores of probbits/lossbuf).
__global__ __launch_bounds__(BLOCK) void k_main(
    const float* __restrict__ predict, const int* __restrict__ target,
    const float* __restrict__ weight, float* __restrict__ psum,
    unsigned* __restrict__ pcs, unsigned* __restrict__ pcv)
{
    __shared__ float wsh[32];
    __shared__ float red_f[4];
    __shared__ unsigned red_a[4], red_b[4];
    int tid = threadIdx.x, bid = blockIdx.x;
    if (tid < NCLS) wsh[tid] = weight[tid];
    __syncthreads();

    Grp r = compute4(predict, target, wsh, (bid * BLOCK + tid) * 4);
    float lsum = r.ls; unsigned scnt = r.sc, vcnt = r.vc;
#pragma unroll
    for (int d = 32; d > 0; d >>= 1) {
        lsum += __shfl_down(lsum, d);
        scnt += __shfl_down(scnt, d);
        vcnt += __shfl_down(vcnt, d);
    }
    if ((tid & 63) == 0) { red_f[tid >> 6] = lsum; red_a[tid >> 6] = scnt; red_b[tid >> 6] = vcnt; }
    __syncthreads();
    if (tid == 0) {
        psum[bid] = red_f[0] + red_f[1] + red_f[2] + red_f[3];
        pcs[bid]  = red_a[0] + red_a[1] + red_a[2] + red_a[3];
        pcv[bid]  = red_b[0] + red_b[1] + red_b[2] + red_b[3];
    }
}

// ---------------------------------------------------------------------------
// K2: reduce partials; decide path; write output on the common path.
// Also zeroes the done-counters used by the fused fallback kernels
// (write-before-read under workspace poisoning: this dispatch always runs
// before any fallback dispatch on the same stream).
__global__ __launch_bounds__(BLOCK) void k_decide(
    const float* __restrict__ psum, const unsigned* __restrict__ pcs,
    const unsigned* __restrict__ pcv, unsigned* __restrict__ state,
    float* __restrict__ out)
{
    __shared__ double red_d[4];
    __shared__ unsigned red_a[4], red_b[4];
    int tid = threadIdx.x;
    double ds = 0.0; unsigned cs = 0, cv = 0;
    for (int i = tid; i < GRID_MAIN; i += BLOCK) {
        ds += (double)psum[i]; cs += pcs[i]; cv += pcv[i];
    }
#pragma unroll
    for (int d = 32; d > 0; d >>= 1) {
        ds += __shfl_down(ds, d); cs += __shfl_down(cs, d); cv += __shfl_down(cv, d);
    }
    if ((tid & 63) == 0) { red_d[tid >> 6] = ds; red_a[tid >> 6] = cs; red_b[tid >> 6] = cv; }
    __syncthreads();
    if (tid == 0) {
        double sum = red_d[0] + red_d[1] + red_d[2] + red_d[3];
        unsigned cb = red_a[0] + red_a[1] + red_a[2] + red_a[3];
        unsigned nv = red_b[0] + red_b[1] + red_b[2] + red_b[3];
        unsigned km = nv - 1u;
        unsigned k  = (MINKEPT < km) ? MINKEPT : km;
        bool common = cb > k;          // k-th order stat < 0.9 => threshold == 0.9
        state[4] = common ? 1u : 0u;
        state[5] = k;
        state[6] = 0u; state[7] = 0u; state[8] = 0u; state[9] = 0u;
        if (common) out[0] = (float)(sum / (double)cb);
    }
}

// ---------------------------------------------------------------------------
// Fallback (exact radix-select) — all guarded, early-exit on common path.
__global__ __launch_bounds__(BLOCK) void k_mat(
    const float* __restrict__ predict, const int* __restrict__ target,
    const float* __restrict__ weight, const unsigned* __restrict__ state,
    unsigned* __restrict__ probbits, float* __restrict__ lossbuf,
    unsigned* __restrict__ hist)
{
    if (state[4]) return;
    __shared__ float wsh[32];
    if (threadIdx.x < NCLS) wsh[threadIdx.x] = weight[threadIdx.x];
    __syncthreads();
    int stride = gridDim.x * BLOCK;
    for (int idx = blockIdx.x * BLOCK + threadIdx.x; idx < NGRP; idx += stride) {
        int g = idx * 4;
        Grp r = compute4(predict, target, wsh, g);
        *(u4*)(probbits + g) = r.pb;
        *(f4*)(lossbuf + g) = r.lo;
    }
    for (int i = blockIdx.x * BLOCK + threadIdx.x; i < NBINS; i += stride) hist[i] = 0;
}

// Fused histogram+scan: every block histograms its strided slice, flushes to
// the global hist, then the LAST finishing block (device-scope counter) scans
// the 8192 bins, advances the radix-select state, and re-zeroes hist.
__global__ __launch_bounds__(BLOCK) void k_hist_scan(
    const unsigned* __restrict__ probbits, unsigned* __restrict__ hist,
    unsigned* __restrict__ state, int level)
{
    if (state[4]) return;
    __shared__ unsigned h[NBINS];
    __shared__ unsigned wtot[4], wpre[4];
    __shared__ unsigned isLast;
    int tid = threadIdx.x;
    for (int i = tid; i < NBINS; i += BLOCK) h[i] = 0;
    __syncthreads();
    unsigned pref = (level == 0) ? 0u : state[0];   // previous level's prefix
    int stride = gridDim.x * BLOCK;
    for (int i = blockIdx.x * BLOCK + tid; i < NPIX; i += stride) {
        unsigned pb = probbits[i];
        if (level == 0) atomicAdd(&h[pb >> 19], 1u);
        else if (level == 1) { if ((pb >> 19) == pref) atomicAdd(&h[(pb >> 6) & (NBINS - 1)], 1u); }
        else                 { if ((pb >> 6)  == pref) atomicAdd(&h[pb & 63u], 1u); }
    }
    __syncthreads();
    for (int i = tid; i < NBINS; i += BLOCK) {
        unsigned c = h[i];
        if (c) atomicAdd(&hist[i], c);
    }
    // last-block election (release: flush our hist updates first)
    __threadfence();
    if (tid == 0) {
        unsigned old = __hip_atomic_fetch_add(&state[6 + level], 1u,
                                              __ATOMIC_ACQ_REL, __HIP_MEMORY_SCOPE_AGENT);
        isLast = (old == (unsigned)gridDim.x - 1u) ? 1u : 0u;
    }
    __syncthreads();
    if (!isLast) return;
    __threadfence();   // acquire: make all blocks' hist updates visible

    // --- scan of 8192 bins by this single block (256 threads x 32 bins) ---
    unsigned vals[32];
    unsigned s = 0;
#pragma unroll
    for (int j = 0; j < 32; ++j) {
        unsigned v = __hip_atomic_load(&hist[tid * 32 + j],
                                       __ATOMIC_RELAXED, __HIP_MEMORY_SCOPE_AGENT);
        vals[j] = v; s += v;
    }
    unsigned x = s;
    int lane = tid & 63, wid = tid >> 6;
    for (int d = 1; d < 64; d <<= 1) {
        unsigned y = __shfl_up(x, d);
        if (lane >= d) x += y;
    }
    if (lane == 63) wtot[wid] = x;
    __syncthreads();
    if (tid == 0) {
        unsigned a = 0;
        for (int i = 0; i < 4; ++i) { wpre[i] = a; a += wtot[i]; }
    }
    __syncthreads();
    unsigned excl = x + wpre[wid] - s;

    unsigned k = (level == 0) ? state[5] : state[1];

    if (s > 0 && k >= excl && k < excl + s) {
        unsigned rem = k - excl;
        unsigned cum = 0, kn = 0; int bsel = 0; bool found = false;
#pragma unroll
        for (int j = 0; j < 32; ++j) {
            if (!found && rem < cum + vals[j]) { bsel = j; kn = rem - cum; found = true; }
            cum += vals[j];
        }
        unsigned bin = (unsigned)(tid * 32 + bsel);
        if (level == 0)      { state[0] = bin;                state[1] = kn; }
        else if (level == 1) { state[0] = (pref << 13) | bin; state[1] = kn; }
        else {
            unsigned tb = (pref << 6) | bin;    // exact k-th order stat bits
            state[2] = __float_as_uint(fmaxf(__uint_as_float(tb), 0.9f));
        }
    }
    __syncthreads();
    for (int i = tid; i < NBINS; i += BLOCK) hist[i] = 0;   // ready for next level
}

// Fused select-reduce + final: per-block partials, last finishing block does
// the final reduction and writes out.
__global__ __launch_bounds__(BLOCK) void k_reduce_final(
    const unsigned* __restrict__ probbits, const float* __restrict__ lossbuf,
    unsigned* __restrict__ state, float* __restrict__ psum,
    unsigned* __restrict__ pcs, float* __restrict__ out)
{
    if (state[4]) return;
    unsigned tb = state[2];
    float s = 0.f; unsigned c = 0;
    int tid = threadIdx.x;
    int stride = gridDim.x * BLOCK;
    for (int i = blockIdx.x * BLOCK + tid; i < NPIX; i += stride) {
        unsigned pb = probbits[i];
        float l = lossbuf[i];
        if (pb < tb) { s += l; c++; }      // uint cmp == float cmp for +floats
    }
#pragma unroll
    for (int d = 32; d > 0; d >>= 1) { s += __shfl_down(s, d); c += __shfl_down(c, d); }
    __shared__ float sd[4];
    __shared__ unsigned cd[4];
    __shared__ unsigned isLast;
    int lane = tid & 63, wid = tid >> 6;
    if (lane == 0) { sd[wid] = s; cd[wid] = c; }
    __syncthreads();
    if (tid == 0) {
        psum[blockIdx.x] = sd[0] + sd[1] + sd[2] + sd[3];
        pcs[blockIdx.x]  = cd[0] + cd[1] + cd[2] + cd[3];
    }
    __threadfence();   // release our partials
    if (tid == 0) {
        unsigned old = __hip_atomic_fetch_add(&state[9], 1u,
                                              __ATOMIC_ACQ_REL, __HIP_MEMORY_SCOPE_AGENT);
        isLast = (old == (unsigned)gridDim.x - 1u) ? 1u : 0u;
    }
    __syncthreads();
    if (!isLast) return;
    __threadfence();   // acquire all blocks' partials

    double ds = 0.0; unsigned ct = 0;
    for (int i = tid; i < (int)gridDim.x; i += BLOCK) {
        float pv; unsigned cvv;
        pv  = __hip_atomic_load(&psum[i], __ATOMIC_RELAXED, __HIP_MEMORY_SCOPE_AGENT);
        cvv = __hip_atomic_load(&pcs[i],  __ATOMIC_RELAXED, __HIP_MEMORY_SCOPE_AGENT);
        ds += (double)pv; ct += cvv;
    }
#pragma unroll
    for (int d = 32; d > 0; d >>= 1) { ds += __shfl_down(ds, d); ct += __shfl_down(ct, d); }
    __shared__ double rd[4];
    __shared__ unsigned ra[4];
    if (lane == 0) { rd[wid] = ds; ra[wid] = ct; }
    __syncthreads();
    if (tid == 0) {
        double dt = rd[0] + rd[1] + rd[2] + rd[3];
        unsigned cc = ra[0] + ra[1] + ra[2] + ra[3];
        out[0] = (float)(dt / (double)cc);
    }
}

// ---------------------------------------------------------------------------
extern "C" void kernel_launch(void* const* d_in, const int* in_sizes, int n_in,
                              void* d_out, int out_size, void* d_ws, size_t ws_size,
                              hipStream_t stream)
{
    const float* predict = (const float*)d_in[0];
    const int*   target  = (const int*)d_in[1];
    const float* weight  = (const float*)d_in[2];
    char* ws = (char*)d_ws;
    float* out = (float*)d_out;

    float*    psum     = (float*)(ws + OFF_PSUM);
    unsigned* pcs      = (unsigned*)(ws + OFF_PCS);
    unsigned* pcv      = (unsigned*)(ws + OFF_PCV);
    unsigned* state    = (unsigned*)(ws + OFF_STATE);
    unsigned* probbits = (unsigned*)(ws + OFF_PROB);
    float*    lossbuf  = (float*)(ws + OFF_LOSS);
    unsigned* hist     = (unsigned*)(ws + OFF_HIST);

    k_main<<<GRID_MAIN, BLOCK, 0, stream>>>(predict, target, weight, psum, pcs, pcv);
    k_decide<<<1, BLOCK, 0, stream>>>(psum, pcs, pcv, state, out);
    // exact fallback chain (early-exits when threshold==0.9 path resolved)
    k_mat<<<1024, BLOCK, 0, stream>>>(predict, target, weight, state,
                                      probbits, lossbuf, hist);
    k_hist_scan<<<512, BLOCK, 0, stream>>>(probbits, hist, state, 0);
    k_hist_scan<<<512, BLOCK, 0, stream>>>(probbits, hist, state, 1);
    k_hist_scan<<<512, BLOCK, 0, stream>>>(probbits, hist, state, 2);
    k_reduce_final<<<512, BLOCK, 0, stream>>>(probbits, lossbuf, state, psum, pcs, out);
}

// Round 2
// 452.505 us; speedup vs baseline: 1.0897x; 1.0178x over previous
//
#include <hip/hip_runtime.h>
#include <stdint.h>

#define NCLS 19
#define HW   (768 * 768)          // 589824
#define NPIX (8 * HW)             // 4718592
#define NGRP (NPIX / 4)           // 1179648 groups of 4 pixels
#define MINKEPT 131072u
#define NBINS 8192
#define BLOCK 256
#define GRID_MAIN (NGRP / BLOCK)  // 4608 blocks, exactly 1 group per thread

// workspace layout (bytes) — all write-before-read, no memset required
#define OFF_PSUM  ((size_t)0)                          // GRID_MAIN f32 partial sums
#define OFF_PCS   ((size_t)GRID_MAIN * 4)              // GRID_MAIN u32 sel-cnt
#define OFF_PCV   ((size_t)GRID_MAIN * 8)              // GRID_MAIN u32 valid-cnt
#define OFF_PROB  ((size_t)GRID_MAIN * 12)             // NPIX u32  (fallback only)
#define OFF_LOSS  (OFF_PROB + (size_t)NPIX * 4)        // NPIX f32  (fallback only)

typedef float    f4 __attribute__((ext_vector_type(4)));
typedef int      i4 __attribute__((ext_vector_type(4)));
typedef unsigned u4 __attribute__((ext_vector_type(4)));

struct Grp { u4 pb; f4 lo; float ls; unsigned sc; unsigned vc; };

// Pure per-group function — fallback recompute is bit-identical to phase 1.
// predict/target are read-once streams -> nontemporal loads (no reuse; the
// inter-iteration workspace poison flushes L2/L3 anyway).
__device__ __forceinline__ Grp compute4(const float* __restrict__ predict,
                                        const int* __restrict__ target,
                                        const float* __restrict__ wsh, int g)
{
    int n = g / HW;
    int p = g - n * HW;
    const float* base = predict + (size_t)n * ((size_t)NCLS * HW) + p;

    i4 t4 = __builtin_nontemporal_load((const i4*)(target + g));
    int tcx = (t4.x == -1) ? 0 : t4.x;
    int tcy = (t4.y == -1) ? 0 : t4.y;
    int tcz = (t4.z == -1) ? 0 : t4.z;
    int tcw = (t4.w == -1) ? 0 : t4.w;

    f4 s  = {0.f, 0.f, 0.f, 0.f};
    f4 vt = {0.f, 0.f, 0.f, 0.f};
#pragma unroll
    for (int c = 0; c < NCLS; ++c) {
        f4 v = __builtin_nontemporal_load((const f4*)(base + (size_t)c * HW));
        s.x += __expf(v.x); s.y += __expf(v.y);
        s.z += __expf(v.z); s.w += __expf(v.w);
        vt.x = (c == tcx) ? v.x : vt.x;
        vt.y = (c == tcy) ? v.y : vt.y;
        vt.z = (c == tcz) ? v.z : vt.z;
        vt.w = (c == tcw) ? v.w : vt.w;
    }

    bool vx = (t4.x != -1), vy = (t4.y != -1), vz = (t4.z != -1), vw = (t4.w != -1);
    float lpx = vt.x - __logf(s.x), lpy = vt.y - __logf(s.y);
    float lpz = vt.z - __logf(s.z), lpw = vt.w - __logf(s.w);
    float px = __expf(lpx), py = __expf(lpy), pz = __expf(lpz), pw = __expf(lpw);

    Grp r;
    r.pb.x = vx ? __float_as_uint(px) : 0x7F800000u;
    r.pb.y = vy ? __float_as_uint(py) : 0x7F800000u;
    r.pb.z = vz ? __float_as_uint(pz) : 0x7F800000u;
    r.pb.w = vw ? __float_as_uint(pw) : 0x7F800000u;
    r.lo.x = vx ? (-wsh[tcx] * lpx) : 0.f;
    r.lo.y = vy ? (-wsh[tcy] * lpy) : 0.f;
    r.lo.z = vz ? (-wsh[tcz] * lpz) : 0.f;
    r.lo.w = vw ? (-wsh[tcw] * lpw) : 0.f;
    bool sx = vx && (px < 0.9f), sy = vy && (py < 0.9f);
    bool sz = vz && (pz < 0.9f), sw = vw && (pw < 0.9f);
    r.ls = (sx ? r.lo.x : 0.f) + (sy ? r.lo.y : 0.f) +
           (sz ? r.lo.z : 0.f) + (sw ? r.lo.w : 0.f);
    r.sc = (unsigned)sx + (unsigned)sy + (unsigned)sz + (unsigned)sw;
    r.vc = (unsigned)vx + (unsigned)vy + (unsigned)vz + (unsigned)vw;
    return r;
}

// ---------------------------------------------------------------------------
// K1: pure-read streaming pass. One 4-pixel group per thread; per-block
// partials (no atomics, no stores of probbits/lossbuf). At the memory
// roofline: 377.5 MB read-once -> ~60 us at 6.3 TB/s achievable.
__global__ __launch_bounds__(BLOCK) void k_main(
    const float* __restrict__ predict, const int* __restrict__ target,
    const float* __restrict__ weight, float* __restrict__ psum,
    unsigned* __restrict__ pcs, unsigned* __restrict__ pcv)
{
    __shared__ float wsh[32];
    __shared__ float red_f[4];
    __shared__ unsigned red_a[4], red_b[4];
    int tid = threadIdx.x, bid = blockIdx.x;
    if (tid < NCLS) wsh[tid] = weight[tid];
    __syncthreads();

    Grp r = compute4(predict, target, wsh, (bid * BLOCK + tid) * 4);
    float lsum = r.ls; unsigned scnt = r.sc, vcnt = r.vc;
#pragma unroll
    for (int d = 32; d > 0; d >>= 1) {
        lsum += __shfl_down(lsum, d);
        scnt += __shfl_down(scnt, d);
        vcnt += __shfl_down(vcnt, d);
    }
    if ((tid & 63) == 0) { red_f[tid >> 6] = lsum; red_a[tid >> 6] = scnt; red_b[tid >> 6] = vcnt; }
    __syncthreads();
    if (tid == 0) {
        psum[bid] = red_f[0] + red_f[1] + red_f[2] + red_f[3];
        pcs[bid]  = red_a[0] + red_a[1] + red_a[2] + red_a[3];
        pcv[bid]  = red_b[0] + red_b[1] + red_b[2] + red_b[3];
    }
}

// ---------------------------------------------------------------------------
// K2: reduce partials; decide path; write output on the common path.
// If (and only if) the rare path is needed (k-th order stat >= 0.9), this
// SINGLE block performs the entire exact OHEM computation sequentially:
// materialize probbits/loss, 3-level radix select with LDS histogram,
// select-reduce, final write. No extra dispatches, no cross-block sync —
// every phase boundary is a __syncthreads(). Slow (ms) but never taken on
// the common path; only correctness matters here.
__global__ __launch_bounds__(BLOCK) void k_decide_fb(
    const float* __restrict__ predict, const int* __restrict__ target,
    const float* __restrict__ weight,
    const float* __restrict__ psum, const unsigned* __restrict__ pcs,
    const unsigned* __restrict__ pcv,
    unsigned* __restrict__ probbits, float* __restrict__ lossbuf,
    float* __restrict__ out)
{
    __shared__ double red_d[4];
    __shared__ unsigned red_a[4], red_b[4];
    __shared__ unsigned sh_common, sh_k;
    __shared__ float wsh[32];
    __shared__ unsigned h[NBINS];
    __shared__ unsigned wtot[4], wpre[4];
    __shared__ unsigned sel_bin, sel_rem;

    int tid = threadIdx.x;
    int lane = tid & 63, wid = tid >> 6;

    // ---- decide (common-path arithmetic identical to previous rounds) ----
    double ds = 0.0; unsigned cs = 0, cv = 0;
    for (int i = tid; i < GRID_MAIN; i += BLOCK) {
        ds += (double)psum[i]; cs += pcs[i]; cv += pcv[i];
    }
#pragma unroll
    for (int d = 32; d > 0; d >>= 1) {
        ds += __shfl_down(ds, d); cs += __shfl_down(cs, d); cv += __shfl_down(cv, d);
    }
    if (lane == 0) { red_d[wid] = ds; red_a[wid] = cs; red_b[wid] = cv; }
    __syncthreads();
    if (tid == 0) {
        double sum = red_d[0] + red_d[1] + red_d[2] + red_d[3];
        unsigned cb = red_a[0] + red_a[1] + red_a[2] + red_a[3];
        unsigned nv = red_b[0] + red_b[1] + red_b[2] + red_b[3];
        unsigned km = nv - 1u;
        unsigned k  = (MINKEPT < km) ? MINKEPT : km;
        bool common = cb > k;          // k-th order stat < 0.9 => threshold == 0.9
        sh_common = common ? 1u : 0u;
        sh_k = k;
        if (common) out[0] = (float)(sum / (double)cb);
    }
    __syncthreads();
    if (sh_common) return;             // block-uniform exit

    // =====================================================================
    // Exact fallback — single block, sequential phases.
    // =====================================================================
    unsigned k = sh_k;
    if (tid < NCLS) wsh[tid] = weight[tid];
    __syncthreads();

    // Phase A: materialize probbits + lossbuf (bit-identical recompute).
    for (int idx = tid; idx < NGRP; idx += BLOCK) {
        int g = idx * 4;
        Grp r = compute4(predict, target, wsh, g);
        *(u4*)(probbits + g) = r.pb;
        *(f4*)(lossbuf + g)  = r.lo;
    }
    __syncthreads();

    // Phase B: 3-level radix select for the exact k-th smallest prob bits.
    unsigned pref = 0, krem = k, tb = 0;
    for (int level = 0; level < 3; ++level) {
        for (int i = tid; i < NBINS; i += BLOCK) h[i] = 0;
        __syncthreads();
        for (int i = tid; i < NPIX; i += BLOCK) {
            unsigned pb = probbits[i];
            if (level == 0) atomicAdd(&h[pb >> 19], 1u);
            else if (level == 1) { if ((pb >> 19) == pref) atomicAdd(&h[(pb >> 6) & (NBINS - 1)], 1u); }
            else                 { if ((pb >> 6)  == pref) atomicAdd(&h[pb & 63u], 1u); }
        }
        __syncthreads();

        // scan of 8192 bins: 256 threads x 32 bins each
        unsigned vals[32];
        unsigned s = 0;
#pragma unroll
        for (int j = 0; j < 32; ++j) { vals[j] = h[tid * 32 + j]; s += vals[j]; }
        unsigned x = s;
        for (int d = 1; d < 64; d <<= 1) {
            unsigned y = __shfl_up(x, d);
            if (lane >= d) x += y;
        }
        if (lane == 63) wtot[wid] = x;
        __syncthreads();
        if (tid == 0) {
            unsigned a = 0;
            for (int i = 0; i < 4; ++i) { wpre[i] = a; a += wtot[i]; }
        }
        __syncthreads();
        unsigned excl = x + wpre[wid] - s;

        if (s > 0 && krem >= excl && krem < excl + s) {   // exactly one thread
            unsigned rem = krem - excl;
            unsigned cum = 0, kn = 0; int bsel = 0; bool found = false;
#pragma unroll
            for (int j = 0; j < 32; ++j) {
                if (!found && rem < cum + vals[j]) { bsel = j; kn = rem - cum; found = true; }
                cum += vals[j];
            }
            sel_bin = (unsigned)(tid * 32 + bsel);
            sel_rem = kn;
        }
        __syncthreads();
        if (level == 0)      { pref = sel_bin;               krem = sel_rem; }
        else if (level == 1) { pref = (pref << 13) | sel_bin; krem = sel_rem; }
        else                 { tb = (pref << 6) | sel_bin; }
        __syncthreads();   // protect h/sel_* before next level's reuse
    }

    // Phase C: threshold = max(kth order stat, 0.9); select-reduce; write.
    unsigned tbits = __float_as_uint(fmaxf(__uint_as_float(tb), 0.9f));
    double sacc = 0.0; unsigned c = 0;
    for (int i = tid; i < NPIX; i += BLOCK) {
        unsigned pb = probbits[i];
        if (pb < tbits) { sacc += (double)lossbuf[i]; c++; }   // uint cmp == float cmp for +floats
    }
#pragma unroll
    for (int d = 32; d > 0; d >>= 1) { sacc += __shfl_down(sacc, d); c += __shfl_down(c, d); }
    if (lane == 0) { red_d[wid] = sacc; red_a[wid] = c; }
    __syncthreads();
    if (tid == 0) {
        double dt = red_d[0] + red_d[1] + red_d[2] + red_d[3];
        unsigned cc = red_a[0] + red_a[1] + red_a[2] + red_a[3];
        out[0] = (float)(dt / (double)cc);
    }
}

// ---------------------------------------------------------------------------
extern "C" void kernel_launch(void* const* d_in, const int* in_sizes, int n_in,
                              void* d_out, int out_size, void* d_ws, size_t ws_size,
                              hipStream_t stream)
{
    const float* predict = (const float*)d_in[0];
    const int*   target  = (const int*)d_in[1];
    const float* weight  = (const float*)d_in[2];
    char* ws = (char*)d_ws;
    float* out = (float*)d_out;

    float*    psum     = (float*)(ws + OFF_PSUM);
    unsigned* pcs      = (unsigned*)(ws + OFF_PCS);
    unsigned* pcv      = (unsigned*)(ws + OFF_PCV);
    unsigned* probbits = (unsigned*)(ws + OFF_PROB);
    float*    lossbuf  = (float*)(ws + OFF_LOSS);

    k_main<<<GRID_MAIN, BLOCK, 0, stream>>>(predict, target, weight, psum, pcs, pcv);
    k_decide_fb<<<1, BLOCK, 0, stream>>>(predict, target, weight,
                                         psum, pcs, pcv, probbits, lossbuf, out);
}